// Round 5
// baseline (113.006 us; speedup 1.0000x reference)
//
#include <hip/hip_runtime.h>

#define TWO_N 8192
#define HALF_N 4096
#define DIM 256
#define PANEL_BYTES 8192                     // 16 rows x 256 el x 2B

#define COLSPLIT 16
#define COLS_PER_BLOCK (TWO_N / COLSPLIT)    // 512
#define PANELS_PER_CS (COLS_PER_BLOCK / 16)  // 32
#define CH_COLS 32
#define CHUNK_BYTES (CH_COLS * DIM * 2)      // 16 KB
#define NCHUNK (COLS_PER_BLOCK / CH_COLS)    // 16

#define ROWS_PER_WAVE 64
#define ROWS_PER_BLOCK 256
#define ROWBLOCKS (TWO_N / ROWS_PER_BLOCK)   // 32

#define KAPPA 14.426950408889634f            // 10*log2(e)
#define LN2 0.6931471805599453f

typedef __attribute__((ext_vector_type(8))) short bf16x8;
typedef __attribute__((ext_vector_type(8))) unsigned short ushort8;
typedef __attribute__((ext_vector_type(4))) float f32x4;

__device__ __forceinline__ float bf2f(unsigned short u) {
  return __uint_as_float(((unsigned int)u) << 16);
}
__device__ __forceinline__ unsigned short f2bf(float f) {
  unsigned int u = __float_as_uint(f);
  return (unsigned short)((u + 0x7FFFu + ((u >> 16) & 1u)) >> 16);
}
__device__ __forceinline__ void async_copy16(void* lds_dst, const void* g_src) {
  __builtin_amdgcn_global_load_lds(
      (const __attribute__((address_space(1))) unsigned int*)g_src,
      (__attribute__((address_space(3))) unsigned int*)lds_dst, 16, 0, 0);
}

// rnB layout: panel p (16 rows), byte offset p*8192 + kk*1024 + (g*16 + r)*16
// holds row (p*16+r), k-elements kk*32 + g*8 .. +8 (as bf16).
// MFMA A/B fragment for lane l = (kgrp*16+lrow): slot l of panel -> linear.

// K1: normalize 16 rows (one panel) per block; write fragment-major rnB.
// Also zero rowsum and out.
__global__ __launch_bounds__(256) void k_norm(const float* __restrict__ zi,
                                              const float* __restrict__ zj,
                                              unsigned short* __restrict__ rnB,
                                              float* __restrict__ rowsum,
                                              float* __restrict__ out) {
  int p = blockIdx.x;
  int wave = threadIdx.x >> 6, lane = threadIdx.x & 63;
  int rp = wave * 4 + (lane >> 4);           // row within panel
  int row = p * 16 + rp;
  int kslot = lane & 15;                     // 16 elems per thread
  int k0 = kslot * 16;
  if (threadIdx.x < 16) rowsum[p * 16 + threadIdx.x] = 0.0f;
  if (p == 0 && threadIdx.x == 0) out[0] = 0.0f;

  const float* src = (row < HALF_N) ? (zi + (size_t)row * DIM)
                                    : (zj + (size_t)(row - HALF_N) * DIM);
  float4 v[4];
  #pragma unroll
  for (int q = 0; q < 4; ++q)
    v[q] = *reinterpret_cast<const float4*>(src + k0 + q * 4);
  float ss = 0.0f;
  #pragma unroll
  for (int q = 0; q < 4; ++q)
    ss += v[q].x * v[q].x + v[q].y * v[q].y + v[q].z * v[q].z + v[q].w * v[q].w;
  #pragma unroll
  for (int m = 1; m <= 8; m <<= 1) ss += __shfl_xor(ss, m, 64);
  float r = rsqrtf(ss);

  ushort8 u0, u1;
  #pragma unroll
  for (int q = 0; q < 2; ++q) {
    u0[q * 4 + 0] = f2bf(v[q].x * r); u0[q * 4 + 1] = f2bf(v[q].y * r);
    u0[q * 4 + 2] = f2bf(v[q].z * r); u0[q * 4 + 3] = f2bf(v[q].w * r);
    u1[q * 4 + 0] = f2bf(v[q + 2].x * r); u1[q * 4 + 1] = f2bf(v[q + 2].y * r);
    u1[q * 4 + 2] = f2bf(v[q + 2].z * r); u1[q * 4 + 3] = f2bf(v[q + 2].w * r);
  }
  int kk = kslot >> 1;
  int g = (kslot & 1) * 2;
  char* pb = (char*)rnB + (size_t)p * PANEL_BYTES + kk * 1024;
  *reinterpret_cast<ushort8*>(pb + (g * 16 + rp) * 16) = u0;
  *reinterpret_cast<ushort8*>(pb + ((g + 1) * 16 + rp) * 16) = u1;
}

// K2: Gram rowsums. 4 waves x 64 rows (4 strips). B staged tri-buffered via
// linear global_load_lds; counted vmcnt keeps 1 chunk in flight across the
// barrier. acc = dot; epilogue exp2(fma(d,K,-K)); diagonal removed in K3.
__global__ __launch_bounds__(256, 2) void k_sim(const unsigned short* __restrict__ rnB,
                                                float* __restrict__ rowsum) {
  __shared__ alignas(16) char lds[3][CHUNK_BYTES];
  int cs = blockIdx.x & (COLSPLIT - 1);      // low bits -> XCD affinity
  int rb = blockIdx.x >> 4;
  int wave = threadIdx.x >> 6, lane = threadIdx.x & 63;
  int lrow = lane & 15, kgrp = lane >> 4;
  int r0 = rb * ROWS_PER_BLOCK + wave * ROWS_PER_WAVE;
  const char* base = (const char*)rnB;

  // A: 4 strips, linear per-wave loads from fragment-major panels.
  bf16x8 a[4][8];
  #pragma unroll
  for (int s = 0; s < 4; ++s) {
    const char* pa = base + (size_t)((r0 >> 4) + s) * PANEL_BYTES + lane * 16;
    #pragma unroll
    for (int kk = 0; kk < 8; ++kk)
      a[s][kk] = *reinterpret_cast<const bf16x8*>(pa + kk * 1024);
  }

  float se[4][4];
  #pragma unroll
  for (int s = 0; s < 4; ++s)
    #pragma unroll
    for (int g = 0; g < 4; ++g) se[s][g] = 0.0f;

  const char* cbase = base + (size_t)(cs * PANELS_PER_CS) * PANEL_BYTES;
  auto stage = [&](int buf, int ch) {
    const char* g = cbase + (size_t)ch * CHUNK_BYTES + wave * 1024 + lane * 16;
    char* d = &lds[buf][wave * 1024];
    #pragma unroll
    for (int q = 0; q < 4; ++q)
      async_copy16(d + q * 4096, g + q * 4096);
  };

  stage(0, 0);
  stage(1, 1);
  __syncthreads();                            // full drain once (prologue)

  #pragma unroll
  for (int ch = 0; ch < NCHUNK; ++ch) {
    if (ch + 2 < NCHUNK) stage((ch + 2) % 3, ch + 2);
    const char* lb = lds[ch % 3] + lane * 16;
    #pragma unroll
    for (int h = 0; h < 2; ++h) {
      f32x4 acc[4];
      #pragma unroll
      for (int s = 0; s < 4; ++s) acc[s] = (f32x4){0.f, 0.f, 0.f, 0.f};
      #pragma unroll
      for (int kk = 0; kk < 8; ++kk) {
        bf16x8 b = *reinterpret_cast<const bf16x8*>(lb + h * 8192 + kk * 1024);
        #pragma unroll
        for (int s = 0; s < 4; ++s)
          acc[s] = __builtin_amdgcn_mfma_f32_16x16x32_bf16(a[s][kk], b, acc[s], 0, 0, 0);
      }
      #pragma unroll
      for (int s = 0; s < 4; ++s)
        #pragma unroll
        for (int g = 0; g < 4; ++g)
          se[s][g] += __builtin_amdgcn_exp2f(fmaf(acc[s][g], KAPPA, -KAPPA));
    }
    // counted-vmcnt barrier: keep stage(ch+2)'s 4 loads in flight; ensure
    // stage(ch+1) complete and our ds_reads of buf[ch%3] retired.
    asm volatile("s_waitcnt lgkmcnt(0)" ::: "memory");
    if (ch + 2 < NCHUNK)
      asm volatile("s_waitcnt vmcnt(4)" ::: "memory");
    else
      asm volatile("s_waitcnt vmcnt(0)" ::: "memory");
    __builtin_amdgcn_s_barrier();
  }

  // reduce over 16 column-lanes, one atomic per row
  #pragma unroll
  for (int s = 0; s < 4; ++s) {
    #pragma unroll
    for (int g = 0; g < 4; ++g) {
      float v = se[s][g];
      #pragma unroll
      for (int m = 1; m <= 8; m <<= 1) v += __shfl_xor(v, m, 64);
      if (lrow == 0) atomicAdd(&rowsum[r0 + 16 * s + kgrp * 4 + g], v);
    }
  }
}

// K3: per pair (i, j=i+N): subtract self terms, lse - pos for both rows.
// Lanes 0-31 hold row i granules, 32-63 row j; shfl_xor(32) pairs them.
__global__ __launch_bounds__(256) void k_rowred(const unsigned short* __restrict__ rnB,
                                               const float* __restrict__ rowsum,
                                               float* __restrict__ out) {
  __shared__ float ls[4];
  int wave = threadIdx.x >> 6, lane = threadIdx.x & 63;
  int q = lane & 31;
  float local = 0.0f;
  #pragma unroll
  for (int t = 0; t < 8; ++t) {
    int i = blockIdx.x * 32 + wave * 8 + t;              // pair 0..4095
    int row = (lane >> 5) ? i + HALF_N : i;
    int panel = row >> 4, r = row & 15;
    const char* addr = (const char*)rnB + (size_t)panel * PANEL_BYTES +
                       (q >> 2) * 1024 + ((q & 3) * 16 + r) * 16;
    ushort8 own = *reinterpret_cast<const ushort8*>(addr);
    int4 ow = *reinterpret_cast<int4*>(&own);
    int4 pw;
    pw.x = __shfl_xor(ow.x, 32, 64); pw.y = __shfl_xor(ow.y, 32, 64);
    pw.z = __shfl_xor(ow.z, 32, 64); pw.w = __shfl_xor(ow.w, 32, 64);
    ushort8 part = *reinterpret_cast<ushort8*>(&pw);
    float dp = 0.0f, sf = 0.0f;
    #pragma unroll
    for (int e = 0; e < 8; ++e) {
      float av = bf2f(own[e]), bv = bf2f(part[e]);
      dp += av * bv;
      sf += av * av;
    }
    #pragma unroll
    for (int m = 1; m <= 16; m <<= 1) {
      dp += __shfl_xor(dp, m, 64);
      sf += __shfl_xor(sf, m, 64);
    }
    if (q == 0) {                     // lanes 0 (row i) and 32 (row j)
      float self = __builtin_amdgcn_exp2f(fmaf(sf, KAPPA, -KAPPA));
      float rs = rowsum[row] - self;
      local += 10.0f + LN2 * __builtin_amdgcn_logf(rs) - 10.0f * dp;
    }
  }
  local += __shfl_xor(local, 32, 64);
  if (lane == 0) ls[wave] = local;
  __syncthreads();
  if (threadIdx.x == 0)
    atomicAdd(out, (ls[0] + ls[1] + ls[2] + ls[3]) * (1.0f / TWO_N));
}

extern "C" void kernel_launch(void* const* d_in, const int* in_sizes, int n_in,
                              void* d_out, int out_size, void* d_ws, size_t ws_size,
                              hipStream_t stream) {
  const float* zi = (const float*)d_in[0];
  const float* zj = (const float*)d_in[1];
  unsigned short* rnB = (unsigned short*)d_ws;                      // 4 MB
  float* rowsum = (float*)((char*)d_ws + (size_t)TWO_N * DIM * 2);  // 32 KB
  float* out = (float*)d_out;

  hipLaunchKernelGGL(k_norm, dim3(TWO_N / 16), dim3(256), 0, stream, zi, zj, rnB, rowsum, out);
  hipLaunchKernelGGL(k_sim, dim3(ROWBLOCKS * COLSPLIT), dim3(256), 0, stream, rnB, rowsum);
  hipLaunchKernelGGL(k_rowred, dim3(HALF_N / 32), dim3(256), 0, stream, rnB, rowsum, out);
}

// Round 6
// 50.205 us; speedup vs baseline: 2.2509x; 2.2509x over previous
//
#include <hip/hip_runtime.h>

#define TWO_N 8192
#define HALF_N 4096
#define DIM 256
#define PANEL_BYTES 8192                     // 16 rows x 256 el x 2B

#define COLSPLIT 16
#define COLS_PER_BLOCK (TWO_N / COLSPLIT)    // 512
#define PANELS_PER_CS (COLS_PER_BLOCK / 16)  // 32
#define CH_COLS 32
#define CHUNK_BYTES (CH_COLS * DIM * 2)      // 16 KB
#define NCHUNK (COLS_PER_BLOCK / CH_COLS)    // 16

#define ROWS_PER_WAVE 32
#define ROWS_PER_BLOCK 128
#define ROWBLOCKS (TWO_N / ROWS_PER_BLOCK)   // 64

#define KAPPA 14.426950408889634f            // 10*log2(e)
#define SQRT_KAPPA 3.798282565f
#define LN2 0.6931471805599453f

typedef __attribute__((ext_vector_type(8))) short bf16x8;
typedef __attribute__((ext_vector_type(8))) unsigned short ushort8;
typedef __attribute__((ext_vector_type(4))) float f32x4;

__device__ __forceinline__ float bf2f(unsigned short u) {
  return __uint_as_float(((unsigned int)u) << 16);
}
__device__ __forceinline__ unsigned short f2bf(float f) {
  unsigned int u = __float_as_uint(f);
  return (unsigned short)((u + 0x7FFFu + ((u >> 16) & 1u)) >> 16);
}
__device__ __forceinline__ void async_copy16(void* lds_dst, const void* g_src) {
  __builtin_amdgcn_global_load_lds(
      (const __attribute__((address_space(1))) unsigned int*)g_src,
      (__attribute__((address_space(3))) unsigned int*)lds_dst, 16, 0, 0);
}

// rnB layout: panel p (16 rows), byte offset p*8192 + kk*1024 + (g*16 + r)*16
// holds row (p*16+r), k-elements kk*32 + g*8 .. +8, as bf16 scaled by
// SQRT_KAPPA. So any MFMA dot of two stored rows = KAPPA * cos-sim.

// K1: normalize 16 rows (one panel) per block; write fragment-major rnB
// scaled by SQRT_KAPPA. Also zero rowsum and out.
__global__ __launch_bounds__(256) void k_norm(const float* __restrict__ zi,
                                              const float* __restrict__ zj,
                                              unsigned short* __restrict__ rnB,
                                              float* __restrict__ rowsum,
                                              float* __restrict__ out) {
  int p = blockIdx.x;
  int wave = threadIdx.x >> 6, lane = threadIdx.x & 63;
  int rp = wave * 4 + (lane >> 4);           // row within panel
  int row = p * 16 + rp;
  int kslot = lane & 15;                     // 16 elems per thread
  int k0 = kslot * 16;
  if (threadIdx.x < 16) rowsum[p * 16 + threadIdx.x] = 0.0f;
  if (p == 0 && threadIdx.x == 0) out[0] = 0.0f;

  const float* src = (row < HALF_N) ? (zi + (size_t)row * DIM)
                                    : (zj + (size_t)(row - HALF_N) * DIM);
  float4 v[4];
  #pragma unroll
  for (int q = 0; q < 4; ++q)
    v[q] = *reinterpret_cast<const float4*>(src + k0 + q * 4);
  float ss = 0.0f;
  #pragma unroll
  for (int q = 0; q < 4; ++q)
    ss += v[q].x * v[q].x + v[q].y * v[q].y + v[q].z * v[q].z + v[q].w * v[q].w;
  #pragma unroll
  for (int m = 1; m <= 8; m <<= 1) ss += __shfl_xor(ss, m, 64);
  float r = rsqrtf(ss) * SQRT_KAPPA;

  ushort8 u0, u1;
  #pragma unroll
  for (int q = 0; q < 2; ++q) {
    u0[q * 4 + 0] = f2bf(v[q].x * r); u0[q * 4 + 1] = f2bf(v[q].y * r);
    u0[q * 4 + 2] = f2bf(v[q].z * r); u0[q * 4 + 3] = f2bf(v[q].w * r);
    u1[q * 4 + 0] = f2bf(v[q + 2].x * r); u1[q * 4 + 1] = f2bf(v[q + 2].y * r);
    u1[q * 4 + 2] = f2bf(v[q + 2].z * r); u1[q * 4 + 3] = f2bf(v[q + 2].w * r);
  }
  int kk = kslot >> 1;
  int g = (kslot & 1) * 2;
  char* pb = (char*)rnB + (size_t)p * PANEL_BYTES + kk * 1024;
  *reinterpret_cast<ushort8*>(pb + (g * 16 + rp) * 16) = u0;
  *reinterpret_cast<ushort8*>(pb + ((g + 1) * 16 + rp) * 16) = u1;
}

// K2: Gram rowsums. 4 waves x 32 rows (2 strips, 64-VGPR A). B double-
// buffered in LDS via linear global_load_lds; acc inits at -KAPPA so the
// epilogue is exp2(acc) + add. Diagonal term included; removed in K3.
__global__ __launch_bounds__(256, 4) void k_sim(const unsigned short* __restrict__ rnB,
                                                float* __restrict__ rowsum) {
  __shared__ alignas(16) char lds[2][CHUNK_BYTES];
  int cs = blockIdx.x & (COLSPLIT - 1);      // low bits -> XCD affinity
  int rb = blockIdx.x >> 4;
  int wave = threadIdx.x >> 6, lane = threadIdx.x & 63;
  int lrow = lane & 15, kgrp = lane >> 4;
  int r0 = rb * ROWS_PER_BLOCK + wave * ROWS_PER_WAVE;
  const char* base = (const char*)rnB;

  // A: 2 strips, linear per-wave loads from fragment-major panels.
  bf16x8 a[2][8];
  #pragma unroll
  for (int s = 0; s < 2; ++s) {
    const char* pa = base + (size_t)((r0 >> 4) + s) * PANEL_BYTES + lane * 16;
    #pragma unroll
    for (int kk = 0; kk < 8; ++kk)
      a[s][kk] = *reinterpret_cast<const bf16x8*>(pa + kk * 1024);
  }

  float se[2][4];
  #pragma unroll
  for (int s = 0; s < 2; ++s)
    #pragma unroll
    for (int g = 0; g < 4; ++g) se[s][g] = 0.0f;

  const char* cbase = base + (size_t)(cs * PANELS_PER_CS) * PANEL_BYTES;
  auto stage = [&](int buf, int ch) {
    const char* gp = cbase + (size_t)ch * CHUNK_BYTES + wave * 1024 + lane * 16;
    char* d = &lds[buf][wave * 1024];
    #pragma unroll
    for (int q = 0; q < 4; ++q)
      async_copy16(d + q * 4096, gp + q * 4096);
  };

  stage(0, 0);
  __syncthreads();

  for (int ch = 0; ch < NCHUNK; ++ch) {
    if (ch + 1 < NCHUNK) stage((ch + 1) & 1, ch + 1);
    const char* lb = lds[ch & 1] + lane * 16;
    #pragma unroll
    for (int h = 0; h < 2; ++h) {
      f32x4 acc0 = {-KAPPA, -KAPPA, -KAPPA, -KAPPA};
      f32x4 acc1 = {-KAPPA, -KAPPA, -KAPPA, -KAPPA};
      #pragma unroll
      for (int kk = 0; kk < 8; ++kk) {
        bf16x8 b = *reinterpret_cast<const bf16x8*>(lb + h * 8192 + kk * 1024);
        acc0 = __builtin_amdgcn_mfma_f32_16x16x32_bf16(a[0][kk], b, acc0, 0, 0, 0);
        acc1 = __builtin_amdgcn_mfma_f32_16x16x32_bf16(a[1][kk], b, acc1, 0, 0, 0);
      }
      #pragma unroll
      for (int g = 0; g < 4; ++g) {
        se[0][g] += __builtin_amdgcn_exp2f(acc0[g]);
        se[1][g] += __builtin_amdgcn_exp2f(acc1[g]);
      }
    }
    __syncthreads();   // drains stage(ch+1)'s vmcnt + our lgkm; buf swap safe
  }

  // reduce over 16 column-lanes, one atomic per row
  #pragma unroll
  for (int s = 0; s < 2; ++s) {
    #pragma unroll
    for (int g = 0; g < 4; ++g) {
      float v = se[s][g];
      #pragma unroll
      for (int m = 1; m <= 8; m <<= 1) v += __shfl_xor(v, m, 64);
      if (lrow == 0) atomicAdd(&rowsum[r0 + 16 * s + kgrp * 4 + g], v);
    }
  }
}

// K3: per pair (i, j=i+N): subtract self term, lse - pos for both rows.
// Stored dots are KAPPA-scaled: pos = LN2*dp, self = exp2(sf - KAPPA).
__global__ __launch_bounds__(256) void k_rowred(const unsigned short* __restrict__ rnB,
                                               const float* __restrict__ rowsum,
                                               float* __restrict__ out) {
  __shared__ float ls[4];
  int wave = threadIdx.x >> 6, lane = threadIdx.x & 63;
  int q = lane & 31;
  float local = 0.0f;
  #pragma unroll
  for (int t = 0; t < 8; ++t) {
    int i = blockIdx.x * 32 + wave * 8 + t;              // pair 0..4095
    int row = (lane >> 5) ? i + HALF_N : i;
    int panel = row >> 4, r = row & 15;
    const char* addr = (const char*)rnB + (size_t)panel * PANEL_BYTES +
                       (q >> 2) * 1024 + ((q & 3) * 16 + r) * 16;
    ushort8 own = *reinterpret_cast<const ushort8*>(addr);
    int4 ow = *reinterpret_cast<int4*>(&own);
    int4 pw;
    pw.x = __shfl_xor(ow.x, 32, 64); pw.y = __shfl_xor(ow.y, 32, 64);
    pw.z = __shfl_xor(ow.z, 32, 64); pw.w = __shfl_xor(ow.w, 32, 64);
    ushort8 part = *reinterpret_cast<ushort8*>(&pw);
    float dp = 0.0f, sf = 0.0f;
    #pragma unroll
    for (int e = 0; e < 8; ++e) {
      float av = bf2f(own[e]), bv = bf2f(part[e]);
      dp += av * bv;
      sf += av * av;
    }
    #pragma unroll
    for (int m = 1; m <= 16; m <<= 1) {
      dp += __shfl_xor(dp, m, 64);
      sf += __shfl_xor(sf, m, 64);
    }
    if (q == 0) {                     // lanes 0 (row i) and 32 (row j)
      float self = __builtin_amdgcn_exp2f(sf - KAPPA);
      float rs = rowsum[row] - self;
      float lse = 10.0f + LN2 * __builtin_amdgcn_logf(rs);  // logf = log2
      local += lse - LN2 * dp;        // pos = 10*d = LN2 * (KAPPA*d)
    }
  }
  local += __shfl_xor(local, 32, 64);
  if (lane == 0) ls[wave] = local;
  __syncthreads();
  if (threadIdx.x == 0)
    atomicAdd(out, (ls[0] + ls[1] + ls[2] + ls[3]) * (1.0f / TWO_N));
}

extern "C" void kernel_launch(void* const* d_in, const int* in_sizes, int n_in,
                              void* d_out, int out_size, void* d_ws, size_t ws_size,
                              hipStream_t stream) {
  const float* zi = (const float*)d_in[0];
  const float* zj = (const float*)d_in[1];
  unsigned short* rnB = (unsigned short*)d_ws;                      // 4 MB
  float* rowsum = (float*)((char*)d_ws + (size_t)TWO_N * DIM * 2);  // 32 KB
  float* out = (float*)d_out;

  hipLaunchKernelGGL(k_norm, dim3(TWO_N / 16), dim3(256), 0, stream, zi, zj, rnB, rowsum, out);
  hipLaunchKernelGGL(k_sim, dim3(ROWBLOCKS * COLSPLIT), dim3(256), 0, stream, rnB, rowsum);
  hipLaunchKernelGGL(k_rowred, dim3(HALF_N / 32), dim3(256), 0, stream, rnB, rowsum, out);
}

// Round 7
// 49.319 us; speedup vs baseline: 2.2913x; 1.0180x over previous
//
#include <hip/hip_runtime.h>

#define TWO_N 8192
#define HALF_N 4096
#define DIM 256
#define PANEL_BYTES 8192                     // 16 rows x 256 el x 2B

#define NBLK 64                              // 8192 / 128 tile-blocks
#define CH_COLS 32
#define CHUNK_BYTES (CH_COLS * DIM * 2)      // 16 KB (2 panels)
#define NCHUNK 4                             // 128 cols / 32

#define ROWS_PER_WAVE 32
#define ROWS_PER_BLOCK 128

#define KAPPA 14.426950408889634f            // 10*log2(e)
#define SQRT_KAPPA 3.798282565f
#define LN2 0.6931471805599453f

typedef __attribute__((ext_vector_type(8))) short bf16x8;
typedef __attribute__((ext_vector_type(8))) unsigned short ushort8;
typedef __attribute__((ext_vector_type(4))) float f32x4;

__device__ __forceinline__ float bf2f(unsigned short u) {
  return __uint_as_float(((unsigned int)u) << 16);
}
__device__ __forceinline__ unsigned short f2bf(float f) {
  unsigned int u = __float_as_uint(f);
  return (unsigned short)((u + 0x7FFFu + ((u >> 16) & 1u)) >> 16);
}
__device__ __forceinline__ void async_copy16(void* lds_dst, const void* g_src) {
  __builtin_amdgcn_global_load_lds(
      (const __attribute__((address_space(1))) unsigned int*)g_src,
      (__attribute__((address_space(3))) unsigned int*)lds_dst, 16, 0, 0);
}

// rnB layout: panel p (16 rows), byte offset p*8192 + kk*1024 + (g*16 + r)*16
// holds row (p*16+r), k-elements kk*32 + g*8 .. +8, as bf16 scaled by
// SQRT_KAPPA. So any MFMA dot of two stored rows = KAPPA * cos-sim.

// K1: normalize 16 rows (one panel) per block; write fragment-major rnB
// scaled by SQRT_KAPPA. Also zero rowsum and out.
__global__ __launch_bounds__(256) void k_norm(const float* __restrict__ zi,
                                              const float* __restrict__ zj,
                                              unsigned short* __restrict__ rnB,
                                              float* __restrict__ rowsum,
                                              float* __restrict__ out) {
  int p = blockIdx.x;
  int wave = threadIdx.x >> 6, lane = threadIdx.x & 63;
  int rp = wave * 4 + (lane >> 4);           // row within panel
  int row = p * 16 + rp;
  int kslot = lane & 15;                     // 16 elems per thread
  int k0 = kslot * 16;
  if (threadIdx.x < 16) rowsum[p * 16 + threadIdx.x] = 0.0f;
  if (p == 0 && threadIdx.x == 0) out[0] = 0.0f;

  const float* src = (row < HALF_N) ? (zi + (size_t)row * DIM)
                                    : (zj + (size_t)(row - HALF_N) * DIM);
  float4 v[4];
  #pragma unroll
  for (int q = 0; q < 4; ++q)
    v[q] = *reinterpret_cast<const float4*>(src + k0 + q * 4);
  float ss = 0.0f;
  #pragma unroll
  for (int q = 0; q < 4; ++q)
    ss += v[q].x * v[q].x + v[q].y * v[q].y + v[q].z * v[q].z + v[q].w * v[q].w;
  #pragma unroll
  for (int m = 1; m <= 8; m <<= 1) ss += __shfl_xor(ss, m, 64);
  float r = rsqrtf(ss) * SQRT_KAPPA;

  ushort8 u0, u1;
  #pragma unroll
  for (int q = 0; q < 2; ++q) {
    u0[q * 4 + 0] = f2bf(v[q].x * r); u0[q * 4 + 1] = f2bf(v[q].y * r);
    u0[q * 4 + 2] = f2bf(v[q].z * r); u0[q * 4 + 3] = f2bf(v[q].w * r);
    u1[q * 4 + 0] = f2bf(v[q + 2].x * r); u1[q * 4 + 1] = f2bf(v[q + 2].y * r);
    u1[q * 4 + 2] = f2bf(v[q + 2].z * r); u1[q * 4 + 3] = f2bf(v[q + 2].w * r);
  }
  int kk = kslot >> 1;
  int g = (kslot & 1) * 2;
  char* pb = (char*)rnB + (size_t)p * PANEL_BYTES + kk * 1024;
  *reinterpret_cast<ushort8*>(pb + (g * 16 + rp) * 16) = u0;
  *reinterpret_cast<ushort8*>(pb + ((g + 1) * 16 + rp) * 16) = u1;
}

// K2: symmetric Gram rowsums. Tile pair {bi, bj}: 128x128. Row-exp-sums go
// to rowsum[bi rows]; column-exp-sums (tile transposed = tile(bj,bi)) go to
// rowsum[bj rows]; diagonal tiles (bi==bj) do rows only. ~2x less MFMA, LDS
// and exp work than the full Gram.
__global__ __launch_bounds__(256, 4) void k_sim(const unsigned short* __restrict__ rnB,
                                                float* __restrict__ rowsum) {
  __shared__ alignas(16) char lds[2][CHUNK_BYTES];
  int bi = blockIdx.x;
  int d = blockIdx.y;
  if (d == 32 && bi >= 32) return;           // dedupe the involutive offset
  int bj = (bi + d) & (NBLK - 1);
  bool diag = (d == 0);

  int wave = threadIdx.x >> 6, lane = threadIdx.x & 63;
  int lrow = lane & 15, kgrp = lane >> 4;
  int r0 = bi * ROWS_PER_BLOCK + wave * ROWS_PER_WAVE;
  const char* base = (const char*)rnB;

  // A: 2 strips (32 rows) per wave, linear loads from fragment-major panels.
  bf16x8 a[2][8];
  #pragma unroll
  for (int s = 0; s < 2; ++s) {
    const char* pa = base + (size_t)(bi * 8 + wave * 2 + s) * PANEL_BYTES + lane * 16;
    #pragma unroll
    for (int kk = 0; kk < 8; ++kk)
      a[s][kk] = *reinterpret_cast<const bf16x8*>(pa + kk * 1024);
  }

  float se[2][4];
  #pragma unroll
  for (int s = 0; s < 2; ++s)
    #pragma unroll
    for (int g = 0; g < 4; ++g) se[s][g] = 0.0f;

  const char* cbase = base + (size_t)(bj * 8) * PANEL_BYTES;
  auto stage = [&](int buf, int ch) {
    const char* gp = cbase + (size_t)ch * CHUNK_BYTES + wave * 1024 + lane * 16;
    char* dst = &lds[buf][wave * 1024];
    #pragma unroll
    for (int q = 0; q < 4; ++q)
      async_copy16(dst + q * 4096, gp + q * 4096);
  };

  stage(0, 0);
  __syncthreads();

  for (int ch = 0; ch < NCHUNK; ++ch) {
    if (ch + 1 < NCHUNK) stage((ch + 1) & 1, ch + 1);
    const char* lb = lds[ch & 1] + lane * 16;
    #pragma unroll
    for (int h = 0; h < 2; ++h) {
      f32x4 acc0 = {-KAPPA, -KAPPA, -KAPPA, -KAPPA};
      f32x4 acc1 = {-KAPPA, -KAPPA, -KAPPA, -KAPPA};
      #pragma unroll
      for (int kk = 0; kk < 8; ++kk) {
        bf16x8 b = *reinterpret_cast<const bf16x8*>(lb + h * 8192 + kk * 1024);
        acc0 = __builtin_amdgcn_mfma_f32_16x16x32_bf16(a[0][kk], b, acc0, 0, 0, 0);
        acc1 = __builtin_amdgcn_mfma_f32_16x16x32_bf16(a[1][kk], b, acc1, 0, 0, 0);
      }
      float scc = 0.0f;
      #pragma unroll
      for (int g = 0; g < 4; ++g) {
        float e0 = __builtin_amdgcn_exp2f(acc0[g]);
        float e1 = __builtin_amdgcn_exp2f(acc1[g]);
        se[0][g] += e0;
        se[1][g] += e1;
        scc += e0 + e1;
      }
      if (!diag) {
        // column sums of this tile -> rows of bj (transposed tile).
        scc += __shfl_xor(scc, 16, 64);
        scc += __shfl_xor(scc, 32, 64);
        if (lane < 16)
          atomicAdd(&rowsum[bj * ROWS_PER_BLOCK + ch * CH_COLS + h * 16 + lane], scc);
      }
    }
    __syncthreads();   // drains stage(ch+1)'s vmcnt + our lgkm; buf swap safe
  }

  // row sums: reduce over 16 column-lanes, one atomic per row
  #pragma unroll
  for (int s = 0; s < 2; ++s) {
    #pragma unroll
    for (int g = 0; g < 4; ++g) {
      float v = se[s][g];
      #pragma unroll
      for (int m = 1; m <= 8; m <<= 1) v += __shfl_xor(v, m, 64);
      if (lrow == 0) atomicAdd(&rowsum[r0 + 16 * s + kgrp * 4 + g], v);
    }
  }
}

// K3: per pair (i, j=i+N): subtract self term, lse - pos for both rows.
// Stored dots are KAPPA-scaled: pos = LN2*dp, self = exp2(sf - KAPPA).
__global__ __launch_bounds__(256) void k_rowred(const unsigned short* __restrict__ rnB,
                                               const float* __restrict__ rowsum,
                                               float* __restrict__ out) {
  __shared__ float ls[4];
  int wave = threadIdx.x >> 6, lane = threadIdx.x & 63;
  int q = lane & 31;
  float local = 0.0f;
  #pragma unroll
  for (int t = 0; t < 8; ++t) {
    int i = blockIdx.x * 32 + wave * 8 + t;              // pair 0..4095
    int row = (lane >> 5) ? i + HALF_N : i;
    int panel = row >> 4, r = row & 15;
    const char* addr = (const char*)rnB + (size_t)panel * PANEL_BYTES +
                       (q >> 2) * 1024 + ((q & 3) * 16 + r) * 16;
    ushort8 own = *reinterpret_cast<const ushort8*>(addr);
    int4 ow = *reinterpret_cast<int4*>(&own);
    int4 pw;
    pw.x = __shfl_xor(ow.x, 32, 64); pw.y = __shfl_xor(ow.y, 32, 64);
    pw.z = __shfl_xor(ow.z, 32, 64); pw.w = __shfl_xor(ow.w, 32, 64);
    ushort8 part = *reinterpret_cast<ushort8*>(&pw);
    float dp = 0.0f, sf = 0.0f;
    #pragma unroll
    for (int e = 0; e < 8; ++e) {
      float av = bf2f(own[e]), bv = bf2f(part[e]);
      dp += av * bv;
      sf += av * av;
    }
    #pragma unroll
    for (int m = 1; m <= 16; m <<= 1) {
      dp += __shfl_xor(dp, m, 64);
      sf += __shfl_xor(sf, m, 64);
    }
    if (q == 0) {                     // lanes 0 (row i) and 32 (row j)
      float self = __builtin_amdgcn_exp2f(sf - KAPPA);
      float rs = rowsum[row] - self;
      float lse = 10.0f + LN2 * __builtin_amdgcn_logf(rs);  // logf = log2
      local += lse - LN2 * dp;        // pos = 10*d = LN2 * (KAPPA*d)
    }
  }
  local += __shfl_xor(local, 32, 64);
  if (lane == 0) ls[wave] = local;
  __syncthreads();
  if (threadIdx.x == 0)
    atomicAdd(out, (ls[0] + ls[1] + ls[2] + ls[3]) * (1.0f / TWO_N));
}

extern "C" void kernel_launch(void* const* d_in, const int* in_sizes, int n_in,
                              void* d_out, int out_size, void* d_ws, size_t ws_size,
                              hipStream_t stream) {
  const float* zi = (const float*)d_in[0];
  const float* zj = (const float*)d_in[1];
  unsigned short* rnB = (unsigned short*)d_ws;                      // 4 MB
  float* rowsum = (float*)((char*)d_ws + (size_t)TWO_N * DIM * 2);  // 32 KB
  float* out = (float*)d_out;

  hipLaunchKernelGGL(k_norm, dim3(TWO_N / 16), dim3(256), 0, stream, zi, zj, rnB, rowsum, out);
  hipLaunchKernelGGL(k_sim, dim3(NBLK, 33), dim3(256), 0, stream, rnB, rowsum);
  hipLaunchKernelGGL(k_rowred, dim3(HALF_N / 32), dim3(256), 0, stream, rnB, rowsum, out);
}